// Round 7
// baseline (219.353 us; speedup 1.0000x reference)
//
#include <hip/hip_runtime.h>
#include <hip/hip_bf16.h>

typedef int   i32x4 __attribute__((ext_vector_type(4)));
typedef unsigned int   u32;
typedef unsigned short u16;
typedef signed char    i8;

#define TOKENS 8192
#define NDIM   4096
#define KDIM   4096
#define BK     64            // K per tile, in i8 elements (= 64 bytes/row)
#define NKT    (KDIM / BK)   // 64 K-tiles

// ---------------------------------------------------------------------------
// Kernel 1: FWHT each row of x (4096 f32), quantize row to int8, per-row scale.
// ---------------------------------------------------------------------------
__global__ __launch_bounds__(64)
void fwht_rows_q8(const float* __restrict__ x, i8* __restrict__ xq,
                  float* __restrict__ xscale) {
  const int row = blockIdx.x;
  const int l   = threadIdx.x;

  const float4* xv = reinterpret_cast<const float4*>(x + (size_t)row * KDIM) + l * 16;
  float v[64];
#pragma unroll
  for (int j = 0; j < 16; ++j) {
    float4 f = xv[j];
    v[4*j+0] = f.x; v[4*j+1] = f.y; v[4*j+2] = f.z; v[4*j+3] = f.w;
  }

#pragma unroll
  for (int h = 1; h < 64; h <<= 1) {
#pragma unroll
    for (int j = 0; j < 64; ++j) {
      if ((j & h) == 0) {
        float a = v[j], b = v[j + h];
        v[j] = a + b; v[j + h] = a - b;
      }
    }
  }

#pragma unroll
  for (int m = 1; m < 64; m <<= 1) {
    const bool up = (l & m) != 0;
#pragma unroll
    for (int j = 0; j < 64; ++j) {
      float p = __shfl_xor(v[j], m, 64);
      v[j] = up ? (p - v[j]) : (v[j] + p);
    }
  }

  float mxu = 0.f;
#pragma unroll
  for (int j = 0; j < 64; ++j) mxu = fmaxf(mxu, fabsf(v[j]));
#pragma unroll
  for (int m = 1; m < 64; m <<= 1) mxu = fmaxf(mxu, __shfl_xor(mxu, m, 64));
  mxu = fmaxf(mxu, 1e-30f);
  const float inv = 127.0f / mxu;

  i8* orow = xq + (size_t)row * KDIM + l * 64;
#pragma unroll
  for (int g = 0; g < 4; ++g) {
    u32 w[4];
#pragma unroll
    for (int q4 = 0; q4 < 4; ++q4) {
      int b0 = __float2int_rn(v[g*16+q4*4+0] * inv);
      int b1 = __float2int_rn(v[g*16+q4*4+1] * inv);
      int b2 = __float2int_rn(v[g*16+q4*4+2] * inv);
      int b3 = __float2int_rn(v[g*16+q4*4+3] * inv);
      b0 = min(127, max(-127, b0)); b1 = min(127, max(-127, b1));
      b2 = min(127, max(-127, b2)); b3 = min(127, max(-127, b3));
      w[q4] = (u32)(b0 & 0xff) | ((u32)(b1 & 0xff) << 8) |
              ((u32)(b2 & 0xff) << 16) | ((u32)(b3 & 0xff) << 24);
    }
    uint4 pk; pk.x = w[0]; pk.y = w[1]; pk.z = w[2]; pk.w = w[3];
    *reinterpret_cast<uint4*>(orow + g * 16) = pk;
  }
  if (l == 0) xscale[row] = mxu * (0.015625f / 127.0f);  // (mx/64)/127
}

// ---------------------------------------------------------------------------
// Kernel 2: pack Q (int32 in [-127,127]) to int8. 16 elems/thread.
// ---------------------------------------------------------------------------
__device__ __forceinline__ u32 pack4(int4 q) {
  return (u32)(q.x & 0xff) | ((u32)(q.y & 0xff) << 8) |
         ((u32)(q.z & 0xff) << 16) | ((u32)(q.w & 0xff) << 24);
}
__global__ __launch_bounds__(256)
void qpack(const int* __restrict__ Q, i8* __restrict__ W8) {
  const size_t idx = ((size_t)blockIdx.x * 256 + threadIdx.x) * 16;
  int4 a = *reinterpret_cast<const int4*>(Q + idx);
  int4 b = *reinterpret_cast<const int4*>(Q + idx + 4);
  int4 c = *reinterpret_cast<const int4*>(Q + idx + 8);
  int4 d = *reinterpret_cast<const int4*>(Q + idx + 12);
  uint4 pk; pk.x = pack4(a); pk.y = pack4(b); pk.z = pack4(c); pk.w = pack4(d);
  *reinterpret_cast<uint4*>(W8 + idx) = pk;
}

// ---------------------------------------------------------------------------
// Kernel 3: int8 GEMM, 2 blocks/CU for cross-block MFMA||LDS overlap.
// BM=256 x BN=128 tile, BK=64, 8 waves in 4(M) x 2(N) grid, 64x64 per wave
// (acc[4][4] = 64 AGPRs -> combined regs ~110 <= 128 -> 16 waves/CU).
// Ring-2 LDS slots of 24 KB (A 16 KB + B 8 KB) = 48 KB -> 2 blocks/CU.
// Per tile: stage t+1, 8 ds_read_b128, 16 MFMA, vmcnt(0), one s_barrier.
// Same validated XOR swizzle (conflict-free) and staging map.
// ---------------------------------------------------------------------------
__global__ __launch_bounds__(512, 4)
void gemm_i8_2b(const i8* __restrict__ A, const i8* __restrict__ B,
                const float* __restrict__ xscale, const float* __restrict__ s,
                const float* __restrict__ bias, float* __restrict__ C) {
  __shared__ __align__(16) i8 lds[2 * 24576];   // 48 KB

  const int th   = threadIdx.x;
  const int wave = th >> 6;
  const int lane = th & 63;

  // L2-locality mapping (bijective, 1024 blocks): XCD x owns nt in {4x..4x+3},
  // mt-major within -> 32 concurrent blocks/XCD share a 2 MB B panel.
  const int b0 = blockIdx.x;
  const int xc = b0 & 7;
  const int i  = b0 >> 3;          // 0..127
  const int mt = i >> 2;           // 0..31
  const int nt = xc * 4 + (i & 3); // 0..31

  // staging: thread th covers tile row (th>>2) [+128 for A's second load],
  // 16 B at pre-swizzled byte column (cancels the read-side XOR).
  const int srow = th >> 2;
  const int scol = ((th & 3) * 16) ^ (((th >> 5) & 1) << 5);
  const i8* gA0 = A + (size_t)(mt * 256 + srow) * KDIM + scol;
  const i8* gA1 = gA0 + (size_t)128 * KDIM;
  const i8* gB0 = B + (size_t)(nt * 128 + srow) * KDIM + scol;

  // wave-uniform LDS staging bases (bytes within a 24576-B slot)
  const int ldsA0 = wave * 1024;           // A rows 16w..16w+15
  const int ldsA1 = 8192 + wave * 1024;    // A rows 128+16w..
  const int ldsB0 = 16384 + wave * 1024;   // B rows 16w..16w+15

#define STAGE(tt, ss) do {                                                      \
    __builtin_amdgcn_global_load_lds(                                           \
      (const __attribute__((address_space(1))) void*)(gA0 + (size_t)(tt) * BK), \
      (__attribute__((address_space(3))) void*)(lds + (ss) * 24576 + ldsA0), 16, 0, 0); \
    __builtin_amdgcn_global_load_lds(                                           \
      (const __attribute__((address_space(1))) void*)(gA1 + (size_t)(tt) * BK), \
      (__attribute__((address_space(3))) void*)(lds + (ss) * 24576 + ldsA1), 16, 0, 0); \
    __builtin_amdgcn_global_load_lds(                                           \
      (const __attribute__((address_space(1))) void*)(gB0 + (size_t)(tt) * BK), \
      (__attribute__((address_space(3))) void*)(lds + (ss) * 24576 + ldsB0), 16, 0, 0); \
  } while (0)

  // MFMA fragment byte offsets within slot (same swizzle as staging)
  const int wm = wave >> 1;       // 0..3 -> C rows wm*64..+64
  const int wn = wave & 1;        // 0..1 -> C cols wn*64..+64
  const int laneRow = lane & 15;
  const int kByte   = (lane >> 4) << 4;
  const int swz     = ((lane >> 3) & 1) << 5;
  const int aOff = (((wm * 64 + laneRow) * 64 + kByte) ^ swz);           // + mi*1024
  const int bOff = (((wn * 64 + laneRow) * 64 + kByte) ^ swz) + 16384;   // + ni*1024

  i32x4 acc[4][4];
#pragma unroll
  for (int mi = 0; mi < 4; ++mi)
#pragma unroll
    for (int ni = 0; ni < 4; ++ni)
      acc[mi][ni] = i32x4{0, 0, 0, 0};

  // prologue: stage tile 0 into slot 0
  STAGE(0, 0);
  asm volatile("s_waitcnt vmcnt(0)" ::: "memory");
  __builtin_amdgcn_s_barrier();

  for (int t = 0; t < NKT; ++t) {
    const char* cur = (const char*)lds + (t & 1) * 24576;
    // stage t+1 into the other slot (its tile t-1 reads finished at the
    // end-of-(t-1) barrier)
    if (t + 1 < NKT) STAGE(t + 1, (t + 1) & 1);

    i32x4 bfr[4], af[4];
#pragma unroll
    for (int ni = 0; ni < 4; ++ni)
      bfr[ni] = *(const i32x4*)(cur + bOff + ni * 1024);
#pragma unroll
    for (int mi = 0; mi < 4; ++mi)
      af[mi] = *(const i32x4*)(cur + aOff + mi * 1024);

    __builtin_amdgcn_s_setprio(1);
#pragma unroll
    for (int mi = 0; mi < 4; ++mi)
#pragma unroll
      for (int ni = 0; ni < 4; ++ni)
        acc[mi][ni] = __builtin_amdgcn_mfma_i32_16x16x64_i8(af[mi], bfr[ni], acc[mi][ni], 0, 0, 0);
    __builtin_amdgcn_s_setprio(0);

    // own 3 stage loads drained (issued ~one full tile ago); then sync block
    asm volatile("s_waitcnt vmcnt(0)" ::: "memory");
    __builtin_amdgcn_s_barrier();
  }
#undef STAGE

  // epilogue: y = acc * (xscale[row] * s[col]) + bias[col]
  const int col0 = nt * 128 + wn * 64 + (lane & 15);
  const int row0 = mt * 256 + wm * 64 + ((lane >> 4) << 2);
  float xs[4][4];
#pragma unroll
  for (int mi = 0; mi < 4; ++mi)
#pragma unroll
    for (int r = 0; r < 4; ++r)
      xs[r][mi] = xscale[row0 + mi * 16 + r];
#pragma unroll
  for (int ni = 0; ni < 4; ++ni) {
    const float sc = s[col0 + ni * 16];
    const float bv = bias[col0 + ni * 16];
#pragma unroll
    for (int mi = 0; mi < 4; ++mi) {
      float* cp = C + (size_t)(row0 + mi * 16) * NDIM + col0 + ni * 16;
#pragma unroll
      for (int r = 0; r < 4; ++r)
        cp[(size_t)r * NDIM] = (float)acc[mi][ni][r] * (xs[r][mi] * sc) + bv;
    }
  }
}

// ---------------------------------------------------------------------------
extern "C" void kernel_launch(void* const* d_in, const int* in_sizes, int n_in,
                              void* d_out, int out_size, void* d_ws, size_t ws_size,
                              hipStream_t stream) {
  (void)in_sizes; (void)n_in; (void)out_size; (void)ws_size;
  const float* x    = (const float*)d_in[0];
  const int*   Q    = (const int*)d_in[1];
  const float* s    = (const float*)d_in[2];
  const float* bias = (const float*)d_in[3];
  float* out = (float*)d_out;

  i8*    xq     = (i8*)d_ws;
  i8*    W8     = xq + (size_t)TOKENS * KDIM;
  float* xscale = (float*)(W8 + (size_t)NDIM * KDIM);

  fwht_rows_q8<<<dim3(TOKENS), dim3(64), 0, stream>>>(x, xq, xscale);
  qpack<<<dim3((NDIM * KDIM) / (256 * 16)), dim3(256), 0, stream>>>(Q, W8);
  gemm_i8_2b<<<dim3((TOKENS / 256) * (NDIM / 128)), dim3(512), 0, stream>>>(
      xq, W8, xscale, s, bias, out);
}

// Round 8
// 210.690 us; speedup vs baseline: 1.0411x; 1.0411x over previous
//
#include <hip/hip_runtime.h>
#include <hip/hip_bf16.h>

typedef int   i32x4 __attribute__((ext_vector_type(4)));
typedef unsigned int   u32;
typedef unsigned short u16;
typedef signed char    i8;

#define TOKENS 8192
#define NDIM   4096
#define KDIM   4096
#define BK     64            // K per tile, in i8 elements (= 64 bytes/row)
#define NKT    (KDIM / BK)   // 64 K-tiles

// ---------------------------------------------------------------------------
// Kernel 1: FWHT each row of x (4096 f32), quantize row to int8, per-row scale.
// ---------------------------------------------------------------------------
__global__ __launch_bounds__(64)
void fwht_rows_q8(const float* __restrict__ x, i8* __restrict__ xq,
                  float* __restrict__ xscale) {
  const int row = blockIdx.x;
  const int l   = threadIdx.x;

  const float4* xv = reinterpret_cast<const float4*>(x + (size_t)row * KDIM) + l * 16;
  float v[64];
#pragma unroll
  for (int j = 0; j < 16; ++j) {
    float4 f = xv[j];
    v[4*j+0] = f.x; v[4*j+1] = f.y; v[4*j+2] = f.z; v[4*j+3] = f.w;
  }

#pragma unroll
  for (int h = 1; h < 64; h <<= 1) {
#pragma unroll
    for (int j = 0; j < 64; ++j) {
      if ((j & h) == 0) {
        float a = v[j], b = v[j + h];
        v[j] = a + b; v[j + h] = a - b;
      }
    }
  }

#pragma unroll
  for (int m = 1; m < 64; m <<= 1) {
    const bool up = (l & m) != 0;
#pragma unroll
    for (int j = 0; j < 64; ++j) {
      float p = __shfl_xor(v[j], m, 64);
      v[j] = up ? (p - v[j]) : (v[j] + p);
    }
  }

  float mxu = 0.f;
#pragma unroll
  for (int j = 0; j < 64; ++j) mxu = fmaxf(mxu, fabsf(v[j]));
#pragma unroll
  for (int m = 1; m < 64; m <<= 1) mxu = fmaxf(mxu, __shfl_xor(mxu, m, 64));
  mxu = fmaxf(mxu, 1e-30f);
  const float inv = 127.0f / mxu;

  i8* orow = xq + (size_t)row * KDIM + l * 64;
#pragma unroll
  for (int g = 0; g < 4; ++g) {
    u32 w[4];
#pragma unroll
    for (int q4 = 0; q4 < 4; ++q4) {
      int b0 = __float2int_rn(v[g*16+q4*4+0] * inv);
      int b1 = __float2int_rn(v[g*16+q4*4+1] * inv);
      int b2 = __float2int_rn(v[g*16+q4*4+2] * inv);
      int b3 = __float2int_rn(v[g*16+q4*4+3] * inv);
      b0 = min(127, max(-127, b0)); b1 = min(127, max(-127, b1));
      b2 = min(127, max(-127, b2)); b3 = min(127, max(-127, b3));
      w[q4] = (u32)(b0 & 0xff) | ((u32)(b1 & 0xff) << 8) |
              ((u32)(b2 & 0xff) << 16) | ((u32)(b3 & 0xff) << 24);
    }
    uint4 pk; pk.x = w[0]; pk.y = w[1]; pk.z = w[2]; pk.w = w[3];
    *reinterpret_cast<uint4*>(orow + g * 16) = pk;
  }
  if (l == 0) xscale[row] = mxu * (0.015625f / 127.0f);  // (mx/64)/127
}

// ---------------------------------------------------------------------------
// Kernel 2: pack Q (int32 in [-127,127]) to int8. 16 elems/thread.
// ---------------------------------------------------------------------------
__device__ __forceinline__ u32 pack4(int4 q) {
  return (u32)(q.x & 0xff) | ((u32)(q.y & 0xff) << 8) |
         ((u32)(q.z & 0xff) << 16) | ((u32)(q.w & 0xff) << 24);
}
__global__ __launch_bounds__(256)
void qpack(const int* __restrict__ Q, i8* __restrict__ W8) {
  const size_t idx = ((size_t)blockIdx.x * 256 + threadIdx.x) * 16;
  int4 a = *reinterpret_cast<const int4*>(Q + idx);
  int4 b = *reinterpret_cast<const int4*>(Q + idx + 4);
  int4 c = *reinterpret_cast<const int4*>(Q + idx + 8);
  int4 d = *reinterpret_cast<const int4*>(Q + idx + 12);
  uint4 pk; pk.x = pack4(a); pk.y = pack4(b); pk.z = pack4(c); pk.w = pack4(d);
  *reinterpret_cast<uint4*>(W8 + idx) = pk;
}

// ---------------------------------------------------------------------------
// Kernel 3: int8 GEMM with m201-style per-phase interleave.
// BM=BN=256, BK=64 (64-B rows), 8 waves (2Mx4N), per-wave 128x64 (acc[8][4]),
// ring-4 LDS slots (128 KB), verified XOR swizzle (0 conflicts measured).
// Per K-tile = 2 phases:
//   P0: {8 ds_read (bf + af mi0-3) || stage(t+2) -> bar -> lgkm(0) ->
//        setprio(1) -> 16 MFMA (mi0-3) -> setprio(0) -> bar}
//   P1: {4 ds_read (af mi4-7) -> vmcnt(4) -> bar -> lgkm(0) ->
//        setprio(1) -> 16 MFMA (mi4-7) -> setprio(0) -> bar}
// Mechanism: waves pass the pre-MFMA barrier with own reads in flight;
// lgkmcnt(0) staggers MFMA entry per wave -> wave k's MFMA cluster overlaps
// waves k+1..7's LDS reads (the m201/m218 counted-wait pipeline).
// vmcnt(4) at P1(t) guarantees tile t+1 fully staged before P0(t+1) reads.
// ---------------------------------------------------------------------------
__global__ __launch_bounds__(512, 2)
void gemm256_i8(const i8* __restrict__ A, const i8* __restrict__ B,
                const float* __restrict__ xscale, const float* __restrict__ s,
                const float* __restrict__ bias, float* __restrict__ C) {
  __shared__ __align__(16) i8 lds[4 * 32768];   // 128 KB

  const int th   = threadIdx.x;
  const int wave = th >> 6;
  const int lane = th & 63;

  // L2-locality mapping (bijective, 512 blocks)
  const int b0 = blockIdx.x;
  const int xc = b0 & 7;
  const int i  = b0 >> 3;
  const int mt = i >> 1;
  const int nt = xc * 2 + (i & 1);

  const int srow = th >> 2;
  const int scol = ((th & 3) * 16) ^ (((th >> 5) & 1) << 5);
  const i8* gA0 = A + (size_t)(mt * 256 + srow) * KDIM + scol;
  const i8* gA1 = gA0 + (size_t)128 * KDIM;
  const i8* gB0 = B + (size_t)(nt * 256 + srow) * KDIM + scol;
  const i8* gB1 = gB0 + (size_t)128 * KDIM;

  const int ldsA0 = wave * 1024;
  const int ldsA1 = 8192 + wave * 1024;
  const int ldsB0 = 16384 + wave * 1024;
  const int ldsB1 = 24576 + wave * 1024;

#define STAGE_A(tt, ss) do {                                                    \
    __builtin_amdgcn_global_load_lds(                                           \
      (const __attribute__((address_space(1))) void*)(gA0 + (size_t)(tt) * BK), \
      (__attribute__((address_space(3))) void*)(lds + (ss) * 32768 + ldsA0), 16, 0, 0); \
    __builtin_amdgcn_global_load_lds(                                           \
      (const __attribute__((address_space(1))) void*)(gA1 + (size_t)(tt) * BK), \
      (__attribute__((address_space(3))) void*)(lds + (ss) * 32768 + ldsA1), 16, 0, 0); \
  } while (0)
#define STAGE_B(tt, ss) do {                                                    \
    __builtin_amdgcn_global_load_lds(                                           \
      (const __attribute__((address_space(1))) void*)(gB0 + (size_t)(tt) * BK), \
      (__attribute__((address_space(3))) void*)(lds + (ss) * 32768 + ldsB0), 16, 0, 0); \
    __builtin_amdgcn_global_load_lds(                                           \
      (const __attribute__((address_space(1))) void*)(gB1 + (size_t)(tt) * BK), \
      (__attribute__((address_space(3))) void*)(lds + (ss) * 32768 + ldsB1), 16, 0, 0); \
  } while (0)

  const int wm = wave >> 2;       // 0..1 -> C rows wm*128..+128
  const int wn = wave & 3;        // 0..3 -> C cols wn*64..+64
  const int laneRow = lane & 15;
  const int kByte   = (lane >> 4) << 4;
  const int swz     = ((lane >> 3) & 1) << 5;
  const int aOff = (((wm * 128 + laneRow) * 64 + kByte) ^ swz);          // + mi*1024
  const int bOff = (((wn * 64 + laneRow) * 64 + kByte) ^ swz) + 16384;   // + ni*1024

  i32x4 acc[8][4];
#pragma unroll
  for (int mi = 0; mi < 8; ++mi)
#pragma unroll
    for (int ni = 0; ni < 4; ++ni)
      acc[mi][ni] = i32x4{0, 0, 0, 0};

  // prologue: stage tiles 0,1 into slots 0,1; ensure tile 0 landed
  STAGE_A(0, 0); STAGE_B(0, 0);
  STAGE_A(1, 1); STAGE_B(1, 1);
  asm volatile("s_waitcnt vmcnt(4)" ::: "memory");
  __builtin_amdgcn_sched_barrier(0);
  __builtin_amdgcn_s_barrier();

  for (int t = 0; t < NKT; ++t) {
    const char* base = (const char*)lds + (t & 3) * 32768;
    i32x4 bfr[4], af[4];

    // ================= phase 0 =================
#pragma unroll
    for (int ni = 0; ni < 4; ++ni)
      bfr[ni] = *(const i32x4*)(base + bOff + ni * 1024);
#pragma unroll
    for (int mi = 0; mi < 4; ++mi)
      af[mi] = *(const i32x4*)(base + aOff + mi * 1024);
    if (t + 2 < NKT) { STAGE_A(t + 2, (t + 2) & 3); STAGE_B(t + 2, (t + 2) & 3); }
    __builtin_amdgcn_s_barrier();
    asm volatile("s_waitcnt lgkmcnt(0)" ::: "memory");
    __builtin_amdgcn_sched_barrier(0);
    __builtin_amdgcn_s_setprio(1);
#pragma unroll
    for (int mi = 0; mi < 4; ++mi)
#pragma unroll
      for (int ni = 0; ni < 4; ++ni)
        acc[mi][ni] = __builtin_amdgcn_mfma_i32_16x16x64_i8(af[mi], bfr[ni], acc[mi][ni], 0, 0, 0);
    __builtin_amdgcn_s_setprio(0);
    __builtin_amdgcn_s_barrier();

    // ================= phase 1 =================
#pragma unroll
    for (int mi = 0; mi < 4; ++mi)
      af[mi] = *(const i32x4*)(base + aOff + 4096 + mi * 1024);
    // counted drain once per K-tile: tile t+1 guaranteed landed for P0(t+1);
    // only tile t+2's 4 loads stay in flight.
    if (t + 2 < NKT) asm volatile("s_waitcnt vmcnt(4)" ::: "memory");
    else             asm volatile("s_waitcnt vmcnt(0)" ::: "memory");
    __builtin_amdgcn_sched_barrier(0);
    __builtin_amdgcn_s_barrier();
    asm volatile("s_waitcnt lgkmcnt(0)" ::: "memory");
    __builtin_amdgcn_sched_barrier(0);
    __builtin_amdgcn_s_setprio(1);
#pragma unroll
    for (int mi = 0; mi < 4; ++mi)
#pragma unroll
      for (int ni = 0; ni < 4; ++ni)
        acc[mi + 4][ni] = __builtin_amdgcn_mfma_i32_16x16x64_i8(af[mi], bfr[ni], acc[mi + 4][ni], 0, 0, 0);
    __builtin_amdgcn_s_setprio(0);
    __builtin_amdgcn_s_barrier();
  }
#undef STAGE_A
#undef STAGE_B

  // epilogue: y = acc * (xscale[row] * s[col]) + bias[col]
  const int col0 = nt * 256 + wn * 64 + (lane & 15);
  const int row0 = mt * 256 + wm * 128 + ((lane >> 4) << 2);
  float xs[4][8];
#pragma unroll
  for (int mi = 0; mi < 8; ++mi)
#pragma unroll
    for (int r = 0; r < 4; ++r)
      xs[r][mi] = xscale[row0 + mi * 16 + r];
#pragma unroll
  for (int ni = 0; ni < 4; ++ni) {
    const float sc = s[col0 + ni * 16];
    const float bv = bias[col0 + ni * 16];
#pragma unroll
    for (int mi = 0; mi < 8; ++mi) {
      float* cp = C + (size_t)(row0 + mi * 16) * NDIM + col0 + ni * 16;
#pragma unroll
      for (int r = 0; r < 4; ++r)
        cp[(size_t)r * NDIM] = (float)acc[mi][ni][r] * (xs[r][mi] * sc) + bv;
    }
  }
}

// ---------------------------------------------------------------------------
extern "C" void kernel_launch(void* const* d_in, const int* in_sizes, int n_in,
                              void* d_out, int out_size, void* d_ws, size_t ws_size,
                              hipStream_t stream) {
  (void)in_sizes; (void)n_in; (void)out_size; (void)ws_size;
  const float* x    = (const float*)d_in[0];
  const int*   Q    = (const int*)d_in[1];
  const float* s    = (const float*)d_in[2];
  const float* bias = (const float*)d_in[3];
  float* out = (float*)d_out;

  i8*    xq     = (i8*)d_ws;
  i8*    W8     = xq + (size_t)TOKENS * KDIM;
  float* xscale = (float*)(W8 + (size_t)NDIM * KDIM);

  fwht_rows_q8<<<dim3(TOKENS), dim3(64), 0, stream>>>(x, xq, xscale);
  qpack<<<dim3((NDIM * KDIM) / (256 * 16)), dim3(256), 0, stream>>>(Q, W8);
  gemm256_i8<<<dim3((TOKENS / 256) * (NDIM / 256)), dim3(512), 0, stream>>>(
      xq, W8, xscale, s, bias, out);
}